// Round 10
// baseline (221.729 us; speedup 1.0000x reference)
//
#include <hip/hip_runtime.h>
#include <math.h>

#define NN 8
#define CC 256
#define HH 112
#define WW 112
#define MIP 8
#define EPS 1e-5f
#define WOFF (NN * HH * CC)       // w-branch offset in pool buffer

typedef float nvec4 __attribute__((ext_vector_type(4)));

// ---------------------------------------------------------------------------
// K1: dual-axis average pooling with BN folded in (BN is per-channel affine,
// commutes with the mean). One block per (n,c) plane.
// REGULAR (allocating) loads on x: lines enter L3 so K3's re-read hits
// (r7 measured 57 MB of HBM re-fetch with the NT evict-first policy; r4/r6
// proved the re-read can be a ~100% L3 hit when x is resident).
// pool layout: h-branch P[(n*HH+h)*CC+c] (bn1 applied);
//              w-branch P[WOFF+(n*WW+w)*CC+c] (bn2 applied).
// ---------------------------------------------------------------------------
__global__ __launch_bounds__(256) void pool_bn_kernel(
    const float* __restrict__ x,
    const float* __restrict__ bn1_g, const float* __restrict__ bn1_b,
    const float* __restrict__ bn1_m, const float* __restrict__ bn1_v,
    const float* __restrict__ bn2_g, const float* __restrict__ bn2_b,
    const float* __restrict__ bn2_m, const float* __restrict__ bn2_v,
    float* __restrict__ pool) {
    __shared__ float rowpart[HH][29];
    __shared__ float4 colpart[8][28];
    const int b = blockIdx.x;                // n*CC + c
    const int n = b / CC;
    const int c = b % CC;
    const int t = threadIdx.x;

    const nvec4* p4 = (const nvec4*)(x + (size_t)b * (HH * WW));

    if (t < 224) {
        const int g = t / 28;                // row group 0..7
        const int j = t % 28;                // float4 column 0..27
        float4 ca = make_float4(0.f, 0.f, 0.f, 0.f);
#pragma unroll
        for (int k = 0; k < 14; ++k) {
            const int r = g + 8 * k;
            nvec4 v = p4[r * 28 + j];        // allocating load -> L3-resident
            ca.x += v.x; ca.y += v.y; ca.z += v.z; ca.w += v.w;
            rowpart[r][j] = v.x + v.y + v.z + v.w;
        }
        colpart[g][j] = ca;
    }
    __syncthreads();

    if (t < HH) {
        // row mean (over w) -> h-branch, bn1 folded
        float s = 0.f;
#pragma unroll
        for (int j = 0; j < 28; ++j) s += rowpart[t][j];
        const float sc = bn1_g[c] * rsqrtf(bn1_v[c] + EPS);
        const float sh = bn1_b[c] - bn1_m[c] * sc;
        pool[((size_t)(n * HH + t)) * CC + c] = (s * (1.0f / WW)) * sc + sh;
    } else if (t < 112 + WW) {
        // column mean (over h) -> w-branch, bn2 folded
        const int w = t - 112;
        const float* cp = (const float*)&colpart[0][0];   // [8][112] floats
        float s = 0.f;
#pragma unroll
        for (int g = 0; g < 8; ++g) s += cp[g * 112 + w];
        const float sc = bn2_g[c] * rsqrtf(bn2_v[c] + EPS);
        const float sh = bn2_b[c] - bn2_m[c] * sc;
        pool[(size_t)WOFF + ((size_t)(n * WW + w)) * CC + c] =
            (s * (1.0f / HH)) * sc + sh;
    }
}

// ---------------------------------------------------------------------------
// K2: conv1x1(C->MIP) -> relu -> conv1x1(MIP->C) -> sigmoid (BN already
// applied by K1). grid = (N*112, 2), 256 threads = one channel each, fully
// coalesced; zero redundancy. In-place update of the pooled buffer.
// ---------------------------------------------------------------------------
__global__ __launch_bounds__(256) void att_kernel(
    float* __restrict__ pool,
    const float* __restrict__ ds_w, const float* __restrict__ ds_b,
    const float* __restrict__ us_w, const float* __restrict__ us_b) {
    __shared__ float s[CC];
    __shared__ float dsh[MIP];

    const int branch = blockIdx.y;
    const int c = threadIdx.x;
    const size_t idx =
        (size_t)branch * WOFF + (size_t)blockIdx.x * CC + c;

    s[c] = pool[idx];
    __syncthreads();

    {
        const int grp = c >> 5;
        const int l = c & 31;
        float partial = 0.f;
#pragma unroll
        for (int k = 0; k < CC / 32; ++k) {
            const int cc = l + k * 32;
            partial += ds_w[grp * CC + cc] * s[cc];
        }
#pragma unroll
        for (int off = 16; off > 0; off >>= 1)
            partial += __shfl_down(partial, off, 32);
        if (l == 0) dsh[grp] = fmaxf(partial + ds_b[grp], 0.f);
    }
    __syncthreads();

    float acc = us_b[c];
#pragma unroll
    for (int m = 0; m < MIP; ++m) acc += us_w[c * MIP + m] * dsh[m];
    pool[idx] = 1.0f / (1.0f + expf(-acc));
}

// ---------------------------------------------------------------------------
// K3: apply + h-swish. One block per (n,c) plane: stage 112 ah + 112 aw into
// LDS, then stream x -> out with the same 224-thread uniform pattern as K1:
// thread (g,j) walks rows g+8k. NT load on x (L3-hit expected, line dead
// after use), NT store on out (write-streaming). aw[4j..4j+3] loop-invariant.
// ---------------------------------------------------------------------------
__global__ __launch_bounds__(256) void apply_kernel(
    const float* __restrict__ x,
    const float* __restrict__ att,
    float* __restrict__ out) {
    __shared__ float ah[HH];
    __shared__ float aw[WW];
    const int b = blockIdx.x;              // n*CC + c
    const int n = b / CC;
    const int c = b % CC;
    const int t = threadIdx.x;

    if (t < HH) {
        ah[t] = att[((size_t)(n * HH + t)) * CC + c];
    } else if (t >= 128 && t < 128 + WW) {
        const int w = t - 128;
        aw[w] = att[(size_t)WOFF + ((size_t)(n * WW + w)) * CC + c];
    }
    __syncthreads();

    if (t < 224) {
        const int g = t / 28;              // row group 0..7
        const int j = t % 28;              // float4 column 0..27
        const nvec4* xp = (const nvec4*)(x + (size_t)b * (HH * WW));
        nvec4* op = (nvec4*)(out + (size_t)b * (HH * WW));
        const float a0 = aw[4 * j + 0];
        const float a1 = aw[4 * j + 1];
        const float a2 = aw[4 * j + 2];
        const float a3 = aw[4 * j + 3];
#pragma unroll
        for (int k = 0; k < 14; ++k) {
            const int r = g + 8 * k;
            const int i = r * 28 + j;
            nvec4 xv = __builtin_nontemporal_load(&xp[i]);
            const float a_h = ah[r];
            nvec4 o;
            o.x = xv.x * (a0 * a_h) + xv.x;
            o.y = xv.y * (a1 * a_h) + xv.y;
            o.z = xv.z * (a2 * a_h) + xv.z;
            o.w = xv.w * (a3 * a_h) + xv.w;
            nvec4 r4;
            r4.x = o.x * fminf(fmaxf(o.x + 3.0f, 0.0f), 6.0f) * (1.0f / 6.0f);
            r4.y = o.y * fminf(fmaxf(o.y + 3.0f, 0.0f), 6.0f) * (1.0f / 6.0f);
            r4.z = o.z * fminf(fmaxf(o.z + 3.0f, 0.0f), 6.0f) * (1.0f / 6.0f);
            r4.w = o.w * fminf(fmaxf(o.w + 3.0f, 0.0f), 6.0f) * (1.0f / 6.0f);
            __builtin_nontemporal_store(r4, &op[i]);
        }
    }
}

extern "C" void kernel_launch(void* const* d_in, const int* in_sizes, int n_in,
                              void* d_out, int out_size, void* d_ws, size_t ws_size,
                              hipStream_t stream) {
    const float* x     = (const float*)d_in[0];
    const float* bn1_g = (const float*)d_in[1];
    const float* bn1_b = (const float*)d_in[2];
    const float* bn1_m = (const float*)d_in[3];
    const float* bn1_v = (const float*)d_in[4];
    const float* bn2_g = (const float*)d_in[5];
    const float* bn2_b = (const float*)d_in[6];
    const float* bn2_m = (const float*)d_in[7];
    const float* bn2_v = (const float*)d_in[8];
    const float* ds_w  = (const float*)d_in[9];
    const float* ds_b  = (const float*)d_in[10];
    const float* us_w  = (const float*)d_in[11];
    const float* us_b  = (const float*)d_in[12];
    float* out  = (float*)d_out;
    float* pool = (float*)d_ws;   // 2*N*112*C*4 = 1.75 MB

    pool_bn_kernel<<<NN * CC, 256, 0, stream>>>(x,
        bn1_g, bn1_b, bn1_m, bn1_v, bn2_g, bn2_b, bn2_m, bn2_v, pool);
    att_kernel<<<dim3(NN * HH, 2), 256, 0, stream>>>(pool,
        ds_w, ds_b, us_w, us_b);
    apply_kernel<<<NN * CC, 256, 0, stream>>>(x, pool, out);
}